// Round 4
// baseline (563.944 us; speedup 1.0000x reference)
//
#include <hip/hip_runtime.h>
#include <hip/hip_bf16.h>

#define NN 16384
#define EE 65536
#define DD 512
#define HH 512

typedef short bf16x8 __attribute__((ext_vector_type(8)));
typedef float f32x4 __attribute__((ext_vector_type(4)));
typedef float float4v __attribute__((ext_vector_type(4)));
typedef unsigned short u16x4 __attribute__((ext_vector_type(4)));

__device__ __forceinline__ float b2f(unsigned short u) {
  union { unsigned int i; float f; } v; v.i = ((unsigned int)u) << 16; return v.f;
}
// round-to-nearest-even f32 -> bf16 bits (finite inputs only)
__device__ __forceinline__ unsigned short f2b(float f) {
  union { float f; unsigned int i; } v; v.f = f;
  unsigned int lsb = (v.i >> 16) & 1u;
  v.i += 0x7fffu + lsb;
  return (unsigned short)(v.i >> 16);
}
__device__ __forceinline__ float sigm(float x) { return 1.f / (1.f + expf(-x)); }

__device__ __forceinline__ void async16(const void* g, void* l) {
  __builtin_amdgcn_global_load_lds(
      (const __attribute__((address_space(1))) void*)g,
      (__attribute__((address_space(3))) void*)l, 16, 0, 0);
}

// ---------------- seg_start: lower_bound per node (seg_ids sorted) ----------
__global__ void k_segstart(const int* __restrict__ seg, int* __restrict__ out) {
  int j = blockIdx.x * blockDim.x + threadIdx.x;
  if (j > NN) return;
  int lo = 0, hi = EE;
  while (lo < hi) { int mid = (lo + hi) >> 1; if (seg[mid] < j) lo = mid + 1; else hi = mid; }
  out[j] = lo;
}

// ---------------- cast x (f32 [NN,512]) into Abig cols 0..511 (bf16, ld=1024)
__global__ void k_cast_x(const float* __restrict__ x, unsigned short* __restrict__ Abig) {
  int idx = (blockIdx.x * 256 + threadIdx.x) * 4;
  if (idx >= NN * DD) return;
  int row = idx >> 9, col = idx & 511;
  float4v v = *(const float4v*)&x[idx];
  u16x4 o; o.x = f2b(v.x); o.y = f2b(v.y); o.z = f2b(v.z); o.w = f2b(v.w);
  *(u16x4*)&Abig[(size_t)row * 1024 + col] = o;
}

// ---------------- h_tilde = segsum(prev_h) -> Abig cols 512..1023 (bf16) ----
__global__ __launch_bounds__(256) void k_htilde(const float* __restrict__ prev_h,
                                                const int* __restrict__ segstart,
                                                unsigned short* __restrict__ Abig) {
  int j = blockIdx.x;
  int t = threadIdx.x;
  int s = segstart[j], e = segstart[j + 1];
  float a0 = 0.f, a1 = 0.f;
  for (int i = s; i < e; ++i) {
    a0 += prev_h[(size_t)i * 512 + t];
    a1 += prev_h[(size_t)i * 512 + t + 256];
  }
  Abig[(size_t)j * 1024 + 512 + t] = f2b(a0);
  Abig[(size_t)j * 1024 + 512 + 256 + t] = f2b(a1);
}

// ---------------- Wbig [2048,1024] bf16: rows 0..1535 = Wc; 1536.. = [Wwf|0]
__global__ void k_build_wbig(const float* __restrict__ Wc, const float* __restrict__ Wwf,
                             unsigned short* __restrict__ Wbig) {
  int idx = (blockIdx.x * 256 + threadIdx.x) * 4;
  if (idx >= 2048 * 1024) return;
  int row = idx >> 10, col = idx & 1023;
  u16x4 o;
  if (row < 1536) {
    float4v v = *(const float4v*)&Wc[(size_t)row * 1024 + col];
    o.x = f2b(v.x); o.y = f2b(v.y); o.z = f2b(v.z); o.w = f2b(v.w);
  } else if (col < 512) {
    float4v v = *(const float4v*)&Wwf[(size_t)(row - 1536) * 512 + col];
    o.x = f2b(v.x); o.y = f2b(v.y); o.z = f2b(v.z); o.w = f2b(v.w);
  } else {
    o.x = 0; o.y = 0; o.z = 0; o.w = 0;
  }
  *(u16x4*)&Wbig[idx] = o;
}

// ---------------- plain f32 -> bf16 cast -----------------------------------
__global__ void k_cast(const float* __restrict__ s, unsigned short* __restrict__ d, int n) {
  int idx = (blockIdx.x * 256 + threadIdx.x) * 4;
  if (idx >= n) return;
  float4v v = *(const float4v*)&s[idx];
  u16x4 o; o.x = f2b(v.x); o.y = f2b(v.y); o.z = f2b(v.z); o.w = f2b(v.w);
  *(u16x4*)&d[idx] = o;
}

// ---------------- bf16 GEMM: C[M,Nout] = A[M,K] @ B[Nout,K]^T ---------------
// m97 structure: 128x128 tile, 4 waves (2x2), 4x4 16x16x32 frags/wave, BK=32,
// global_load_lds width 16, single-buffered LDS (2 barriers / K-step).
#define BM 128
#define BN 128
#define BK 32

__global__ __launch_bounds__(256) void gemm_bt_kernel(
    const unsigned short* __restrict__ A, const unsigned short* __restrict__ B,
    unsigned short* __restrict__ C, int M, int Nout, int K) {
  __shared__ unsigned short lA[BM * BK];
  __shared__ unsigned short lB[BN * BK];
  const int t = threadIdx.x;
  const int w = t >> 6;
  const int l = t & 63;
  const int wr = w >> 1;
  const int wc = w & 1;
  const int row0 = blockIdx.y * BM;
  const int col0 = blockIdx.x * BN;
  const int lr = l & 15;
  const int lk = (l >> 4) * 8;
  const int crow = t >> 2;         // staging chunk row (r=0)
  const int ccol = (t & 3) * 8;

  f32x4 acc[4][4] = {};

  for (int k0 = 0; k0 < K; k0 += BK) {
    // stage A tile [128][32] and B tile [128][32], 16B/lane, linear LDS
    async16(A + (size_t)(row0 + crow) * K + (k0 + ccol), &lA[(size_t)(w * 64) * 8]);
    async16(A + (size_t)(row0 + 64 + crow) * K + (k0 + ccol), &lA[(size_t)(256 + w * 64) * 8]);
    async16(B + (size_t)(col0 + crow) * K + (k0 + ccol), &lB[(size_t)(w * 64) * 8]);
    async16(B + (size_t)(col0 + 64 + crow) * K + (k0 + ccol), &lB[(size_t)(256 + w * 64) * 8]);
    __syncthreads();   // drains vmcnt before any wave reads LDS

    bf16x8 af[4], bfv[4];
#pragma unroll
    for (int m = 0; m < 4; ++m)
      af[m] = *(const bf16x8*)&lA[(wr * 64 + m * 16 + lr) * BK + lk];
#pragma unroll
    for (int n = 0; n < 4; ++n)
      bfv[n] = *(const bf16x8*)&lB[(wc * 64 + n * 16 + lr) * BK + lk];
#pragma unroll
    for (int m = 0; m < 4; ++m)
#pragma unroll
      for (int n = 0; n < 4; ++n)
        acc[m][n] = __builtin_amdgcn_mfma_f32_16x16x32_bf16(af[m], bfv[n], acc[m][n], 0, 0, 0);
    __syncthreads();   // LDS reuse fence
  }

  // epilogue: C/D layout col=lane&15, row=(lane>>4)*4+reg  (m89/m91 verified)
#pragma unroll
  for (int m = 0; m < 4; ++m) {
    const int rb = row0 + wr * 64 + m * 16 + (l >> 4) * 4;
#pragma unroll
    for (int n = 0; n < 4; ++n) {
      const int cb = col0 + wc * 64 + n * 16 + lr;
#pragma unroll
      for (int r = 0; r < 4; ++r)
        C[(size_t)(rb + r) * Nout + cb] = f2b(acc[m][n][r]);
    }
  }
}

// ---------------- final fused elementwise + fc_term segment sum -------------
// big: [NN,2048] bf16 = [z_i | z_o | z_u | f_inputs(no bias)]
// fh:  [EE,512]  bf16 = prev_h @ Wuf^T (no bias)
__global__ __launch_bounds__(256) void k_final(
    const unsigned short* __restrict__ big, const unsigned short* __restrict__ fh,
    const float* __restrict__ prev_c, const int* __restrict__ segstart,
    const float* __restrict__ bc, const float* __restrict__ bwf,
    const float* __restrict__ bufv, float* __restrict__ out) {
  int j = blockIdx.x;
  int t = threadIdx.x;
  int h = t * 2;
  int s = segstart[j], e = segstart[j + 1];
  const unsigned short* bj = big + (size_t)j * 2048;
  float zi0 = b2f(bj[h])        + bc[h];
  float zi1 = b2f(bj[h + 1])    + bc[h + 1];
  float zo0 = b2f(bj[512 + h])  + bc[512 + h];
  float zo1 = b2f(bj[513 + h])  + bc[513 + h];
  float zu0 = b2f(bj[1024 + h]) + bc[1024 + h];
  float zu1 = b2f(bj[1025 + h]) + bc[1025 + h];
  float fi0 = b2f(bj[1536 + h]) + bwf[h]     + bufv[h];
  float fi1 = b2f(bj[1537 + h]) + bwf[h + 1] + bufv[h + 1];
  float fc0 = 0.f, fc1 = 0.f;
  for (int i = s; i < e; ++i) {
    unsigned int ff = *(const unsigned int*)&fh[(size_t)i * 512 + h];
    float2 pc = *(const float2*)&prev_c[(size_t)i * 512 + h];
    fc0 += sigm(fi0 + b2f((unsigned short)(ff & 0xffffu))) * pc.x;
    fc1 += sigm(fi1 + b2f((unsigned short)(ff >> 16)))     * pc.y;
  }
  float c0 = sigm(zi0) * tanhf(zu0) + fc0;
  float c1 = sigm(zi1) * tanhf(zu1) + fc1;
  size_t ob = (size_t)j * 512 + h;
  out[ob]     = c0;
  out[ob + 1] = c1;
  out[(size_t)NN * 512 + ob]     = sigm(zo0) * tanhf(c0);
  out[(size_t)NN * 512 + ob + 1] = sigm(zo1) * tanhf(c1);
}

extern "C" void kernel_launch(void* const* d_in, const int* in_sizes, int n_in,
                              void* d_out, int out_size, void* d_ws, size_t ws_size,
                              hipStream_t stream) {
  const float* x      = (const float*)d_in[0];
  const float* prev_c = (const float*)d_in[1];
  const float* prev_h = (const float*)d_in[2];
  const int*   seg    = (const int*)d_in[3];
  const float* Wc     = (const float*)d_in[4];
  const float* bc     = (const float*)d_in[5];
  const float* Wwf    = (const float*)d_in[6];
  const float* bwf    = (const float*)d_in[7];
  const float* Wuf    = (const float*)d_in[8];
  const float* bufv   = (const float*)d_in[9];

  char* ws = (char*)d_ws;
  size_t off = 0;
  unsigned short* Abig   = (unsigned short*)(ws + off); off += (size_t)NN * 1024 * 2;   // [NN,1024] = [x|h_tilde]
  unsigned short* Wbig   = (unsigned short*)(ws + off); off += (size_t)2048 * 1024 * 2; // [Wc;Wwf|0]
  unsigned short* bigout = (unsigned short*)(ws + off); off += (size_t)NN * 2048 * 2;   // z_i,z_o,z_u,f_in
  unsigned short* phb    = (unsigned short*)(ws + off); off += (size_t)EE * 512 * 2;    // prev_h bf16
  unsigned short* Wufb   = (unsigned short*)(ws + off); off += (size_t)512 * 512 * 2;
  unsigned short* fhout  = (unsigned short*)(ws + off); off += (size_t)EE * 512 * 2;    // f_hiddens
  int* segstart          = (int*)(ws + off);            off += (size_t)(NN + 1) * 4;

  k_segstart<<<(NN + 256) / 256, 256, 0, stream>>>(seg, segstart);
  k_cast_x<<<(NN * DD / 4 + 255) / 256, 256, 0, stream>>>(x, Abig);
  k_htilde<<<NN, 256, 0, stream>>>(prev_h, segstart, Abig);
  k_build_wbig<<<(2048 * 1024 / 4 + 255) / 256, 256, 0, stream>>>(Wc, Wwf, Wbig);
  k_cast<<<(EE * HH / 4 + 255) / 256, 256, 0, stream>>>(prev_h, phb, EE * HH);
  k_cast<<<(HH * HH / 4 + 255) / 256, 256, 0, stream>>>(Wuf, Wufb, HH * HH);

  gemm_bt_kernel<<<dim3(2048 / BN, NN / BM), 256, 0, stream>>>(Abig, Wbig, bigout, NN, 2048, 1024);
  gemm_bt_kernel<<<dim3(512 / BN, EE / BM), 256, 0, stream>>>(phb, Wufb, fhout, EE, 512, 512);

  k_final<<<NN, 256, 0, stream>>>(bigout, fhout, prev_c, segstart, bc, bwf, bufv, (float*)d_out);
}